// Round 10
// baseline (192.723 us; speedup 1.0000x reference)
//
#include <hip/hip_runtime.h>

#define CH 256

// DPP helper: v += dpp_move(v); bound_ctrl=true => out-of-range lanes read 0.
template <int CTRL>
__device__ __forceinline__ float dppAdd(float v) {
    const int m = __builtin_amdgcn_update_dpp(0, __builtin_bit_cast(int, v), CTRL, 0xf, 0xf, true);
    return v + __builtin_bit_cast(float, m);
}

#define OPAQUE4(v) asm volatile("" : "+v"((v).x), "+v"((v).y), "+v"((v).z), "+v"((v).w))

// ---------------- embed + fc_input v2 (FROZEN from round 9)
__global__ __launch_bounds__(256) void embed_fc2_kernel(
    const int* __restrict__ x,
    const float* __restrict__ e0a, const float* __restrict__ e1a, const float* __restrict__ e2a,
    const float* __restrict__ Wina, const float* __restrict__ bina, float* __restrict__ h0a,
    const float* __restrict__ e0b, const float* __restrict__ e1b, const float* __restrict__ e2b,
    const float* __restrict__ Winb, const float* __restrict__ binb, float* __restrict__ h0b,
    const int blocksPer)
{
    __shared__ __align__(16) float eT[128][32];
    int bid = blockIdx.x;
    const float *e0, *e1, *e2, *Win, *bin;
    float* h0;
    if (bid < blocksPer) { e0 = e0a; e1 = e1a; e2 = e2a; Win = Wina; bin = bina; h0 = h0a; }
    else { bid -= blocksPer; e0 = e0b; e1 = e1b; e2 = e2b; Win = Winb; bin = binb; h0 = h0b; }

    const int row0 = bid * 32;
    const int t = threadIdx.x;
    const int w = t >> 6, l = t & 63;
    const int r = l & 31;
    const int kcBase = 2 * w + (l >> 5);

#pragma unroll
    for (int j = 0; j < 4; ++j) {
        const int kc = kcBase + 8 * j;
        const int k0 = kc * 4;
        const int row = row0 + r;
        float4 v;
        if (kc < 16)      v = *(const float4*)(e0 + (size_t)x[row * 3 + 0] * 64 + k0);
        else if (kc < 24) v = *(const float4*)(e1 + (size_t)x[row * 3 + 1] * 32 + (k0 - 64));
        else              v = *(const float4*)(e2 + (size_t)x[row * 3 + 2] * 32 + (k0 - 96));
        eT[k0 + 0][r] = v.x; eT[k0 + 1][r] = v.y; eT[k0 + 2][r] = v.z; eT[k0 + 3][r] = v.w;
    }
    __syncthreads();

    const float4 bb = *(const float4*)(bin + l * 4);
    float acc[8][4];
#pragma unroll
    for (int rr = 0; rr < 8; ++rr) {
        acc[rr][0] = bb.x; acc[rr][1] = bb.y; acc[rr][2] = bb.z; acc[rr][3] = bb.w;
    }
#pragma unroll 4
    for (int k = 0; k < 128; ++k) {
        const float4 wv = *(const float4*)(Win + (size_t)k * 256 + l * 4);
        const float4 ea = *(const float4*)&eT[k][w * 8];
        const float4 eb = *(const float4*)&eT[k][w * 8 + 4];
        const float ev[8] = {ea.x, ea.y, ea.z, ea.w, eb.x, eb.y, eb.z, eb.w};
#pragma unroll
        for (int rr = 0; rr < 8; ++rr) {
            acc[rr][0] += ev[rr] * wv.x; acc[rr][1] += ev[rr] * wv.y;
            acc[rr][2] += ev[rr] * wv.z; acc[rr][3] += ev[rr] * wv.w;
        }
    }
#pragma unroll
    for (int rr = 0; rr < 8; ++rr) {
        float4 o = make_float4(acc[rr][0], acc[rr][1], acc[rr][2], acc[rr][3]);
        *(float4*)(h0 + (size_t)(row0 + w * 8 + rr) * 256 + l * 4) = o;
    }
}

// ---------------- FUSED TAIL: fc_out (both branches) + full semantic integration
// per 16-row block:
//  gemm A (K=256): sim = C0@Wouts+bouts, cor = C1@Woutc+boutc   -> regs + simT/corT
//  gemm B (K=128): S = sim@Ws2c, P = cor@Wc2s                   -> regs + ST/PT
//  gemm C (K=128): T1 = S@Wc2s, T2 = P@Ws2c                     -> regs
//  z2sim = c0*sim + c1*P + c2*T1 ; z2cor = c0*cor + c1*S + c2*T2
// wave w owns rows w*4..w*4+4; lane owns cols 2l..2l+2.
// xT stride 17: transposed writes are 2-way bank aliasing (free); reads are
// 4x broadcast b32 per k (stride 17*4B is not 16B-aligned, so no b128).
__global__ __launch_bounds__(256) void tail_fused_kernel(
    const float* __restrict__ C0, const float* __restrict__ C1,
    const float* __restrict__ Wouts, const float* __restrict__ bouts,
    const float* __restrict__ Woutc, const float* __restrict__ boutc,
    const float* __restrict__ Ws2c, const float* __restrict__ Wc2s,
    const float* __restrict__ a1p, const float* __restrict__ a2p,
    const float* __restrict__ b2p,
    float* __restrict__ outSim, float* __restrict__ outCor)
{
    __shared__ __align__(16) float c0T[256][16];
    __shared__ __align__(16) float c1T[256][16];
    __shared__ float xT0[128][17];   // simT, later ST
    __shared__ float xT1[128][17];   // corT, later PT

    const int t = threadIdx.x;
    const int w = t >> 6, l = t & 63;
    const int row0 = blockIdx.x * 16;          // 6000 = 375*16 exactly

    // stage C0T/C1T: thread -> (row = t>>4, k-chunk = t&15), coalesced reads
    {
        const int row = t >> 4;
        const int kc  = t & 15;
        const float4* s0 = (const float4*)(C0 + (size_t)(row0 + row) * 256);
        const float4* s1 = (const float4*)(C1 + (size_t)(row0 + row) * 256);
#pragma unroll
        for (int j = 0; j < 4; ++j) {
            const int kq = kc + 16 * j;
            const int k0 = 4 * kq;
            float4 v = s0[kq];
            c0T[k0 + 0][row] = v.x; c0T[k0 + 1][row] = v.y;
            c0T[k0 + 2][row] = v.z; c0T[k0 + 3][row] = v.w;
            v = s1[kq];
            c1T[k0 + 0][row] = v.x; c1T[k0 + 1][row] = v.y;
            c1T[k0 + 2][row] = v.z; c1T[k0 + 3][row] = v.w;
        }
    }
    __syncthreads();

    const int r0 = w * 4;
    const int cc = l * 2;

    // ---- gemm A (K=256): sim, cor
    float sim[4][2], cor[4][2];
    {
        const float2 bs = *(const float2*)(bouts + cc);
        const float2 bc = *(const float2*)(boutc + cc);
#pragma unroll
        for (int rr = 0; rr < 4; ++rr) {
            sim[rr][0] = bs.x; sim[rr][1] = bs.y;
            cor[rr][0] = bc.x; cor[rr][1] = bc.y;
        }
    }
#pragma unroll 4
    for (int k = 0; k < 256; ++k) {
        const float4 a0 = *(const float4*)&c0T[k][r0];
        const float4 a1v = *(const float4*)&c1T[k][r0];
        const float2 wsv = *(const float2*)(Wouts + (size_t)k * 128 + cc);
        const float2 wcv = *(const float2*)(Woutc + (size_t)k * 128 + cc);
        const float e0[4] = {a0.x, a0.y, a0.z, a0.w};
        const float e1[4] = {a1v.x, a1v.y, a1v.z, a1v.w};
#pragma unroll
        for (int rr = 0; rr < 4; ++rr) {
            sim[rr][0] += e0[rr] * wsv.x; sim[rr][1] += e0[rr] * wsv.y;
            cor[rr][0] += e1[rr] * wcv.x; cor[rr][1] += e1[rr] * wcv.y;
        }
    }
    // write simT/corT (stride 17 -> 2-way aliasing, free)
#pragma unroll
    for (int rr = 0; rr < 4; ++rr) {
        xT0[cc + 0][r0 + rr] = sim[rr][0]; xT0[cc + 1][r0 + rr] = sim[rr][1];
        xT1[cc + 0][r0 + rr] = cor[rr][0]; xT1[cc + 1][r0 + rr] = cor[rr][1];
    }
    __syncthreads();

    // ---- gemm B (K=128): S = sim@Ws2c, P = cor@Wc2s
    float S[4][2], P[4][2];
#pragma unroll
    for (int rr = 0; rr < 4; ++rr) S[rr][0] = S[rr][1] = P[rr][0] = P[rr][1] = 0.f;
#pragma unroll 4
    for (int k = 0; k < 128; ++k) {
        const float s0 = xT0[k][r0 + 0], s1 = xT0[k][r0 + 1],
                    s2 = xT0[k][r0 + 2], s3 = xT0[k][r0 + 3];
        const float p0 = xT1[k][r0 + 0], p1 = xT1[k][r0 + 1],
                    p2 = xT1[k][r0 + 2], p3 = xT1[k][r0 + 3];
        const float2 wS = *(const float2*)(Ws2c + (size_t)k * 128 + cc);
        const float2 wC = *(const float2*)(Wc2s + (size_t)k * 128 + cc);
        S[0][0] += s0 * wS.x; S[0][1] += s0 * wS.y;
        S[1][0] += s1 * wS.x; S[1][1] += s1 * wS.y;
        S[2][0] += s2 * wS.x; S[2][1] += s2 * wS.y;
        S[3][0] += s3 * wS.x; S[3][1] += s3 * wS.y;
        P[0][0] += p0 * wC.x; P[0][1] += p0 * wC.y;
        P[1][0] += p1 * wC.x; P[1][1] += p1 * wC.y;
        P[2][0] += p2 * wC.x; P[2][1] += p2 * wC.y;
        P[3][0] += p3 * wC.x; P[3][1] += p3 * wC.y;
    }
    __syncthreads();                 // everyone done reading simT/corT
    // overwrite with ST/PT
#pragma unroll
    for (int rr = 0; rr < 4; ++rr) {
        xT0[cc + 0][r0 + rr] = S[rr][0]; xT0[cc + 1][r0 + rr] = S[rr][1];
        xT1[cc + 0][r0 + rr] = P[rr][0]; xT1[cc + 1][r0 + rr] = P[rr][1];
    }
    __syncthreads();

    // ---- gemm C (K=128): T1 = S@Wc2s, T2 = P@Ws2c
    float T1[4][2], T2[4][2];
#pragma unroll
    for (int rr = 0; rr < 4; ++rr) T1[rr][0] = T1[rr][1] = T2[rr][0] = T2[rr][1] = 0.f;
#pragma unroll 4
    for (int k = 0; k < 128; ++k) {
        const float s0 = xT0[k][r0 + 0], s1 = xT0[k][r0 + 1],
                    s2 = xT0[k][r0 + 2], s3 = xT0[k][r0 + 3];
        const float p0 = xT1[k][r0 + 0], p1 = xT1[k][r0 + 1],
                    p2 = xT1[k][r0 + 2], p3 = xT1[k][r0 + 3];
        const float2 wC = *(const float2*)(Wc2s + (size_t)k * 128 + cc);
        const float2 wS = *(const float2*)(Ws2c + (size_t)k * 128 + cc);
        T1[0][0] += s0 * wC.x; T1[0][1] += s0 * wC.y;
        T1[1][0] += s1 * wC.x; T1[1][1] += s1 * wC.y;
        T1[2][0] += s2 * wC.x; T1[2][1] += s2 * wC.y;
        T1[3][0] += s3 * wC.x; T1[3][1] += s3 * wC.y;
        T2[0][0] += p0 * wS.x; T2[0][1] += p0 * wS.y;
        T2[1][0] += p1 * wS.x; T2[1][1] += p1 * wS.y;
        T2[2][0] += p2 * wS.x; T2[2][1] += p2 * wS.y;
        T2[3][0] += p3 * wS.x; T2[3][1] += p3 * wS.y;
    }

    // ---- combine + store
    const float a1 = *a1p, a2 = *a2p, b2 = *b2p;
    const float k0 = 1.f - a2 - b2;
    const float k1 = a2 + b2 * (1.f - a1);
    const float k2 = b2 * a1;
#pragma unroll
    for (int rr = 0; rr < 4; ++rr) {
        const size_t idx = (size_t)(row0 + r0 + rr) * 128 + cc;
        float2 oS, oC;
        oS.x = k0 * sim[rr][0] + k1 * P[rr][0] + k2 * T1[rr][0];
        oS.y = k0 * sim[rr][1] + k1 * P[rr][1] + k2 * T1[rr][1];
        oC.x = k0 * cor[rr][0] + k1 * S[rr][0] + k2 * T2[rr][0];
        oC.y = k0 * cor[rr][1] + k1 * S[rr][1] + k2 * T2[rr][1];
        *(float2*)(outSim + idx) = oS;
        *(float2*)(outCor + idx) = oC;
    }
}

// ---------------- generic 32-row register-tiled GEMM (fallback path only)
template <int KD, int MODE>
__global__ __launch_bounds__(256) void gemm32_kernel(
    const float* __restrict__ ina, const float* __restrict__ Wa,
    const float* __restrict__ auxa, const float* __restrict__ aux2a, float* __restrict__ oa,
    const float* __restrict__ inb, const float* __restrict__ Wb,
    const float* __restrict__ auxb, const float* __restrict__ aux2b, float* __restrict__ ob,
    const int blocksPer, const int nRows,
    const float* __restrict__ a1p, const float* __restrict__ a2p, const float* __restrict__ b2p)
{
    __shared__ __align__(16) float inT[KD][32];
    int bid = blockIdx.x;
    const float *in, *W, *aux, *aux2; float* outp;
    if (bid < blocksPer) { in = ina; W = Wa; aux = auxa; aux2 = aux2a; outp = oa; }
    else { bid -= blocksPer; in = inb; W = Wb; aux = auxb; aux2 = aux2b; outp = ob; }

    const int row0 = bid * 32;
    const int t = threadIdx.x;
    const int w = t >> 6, l = t & 63;
    const int r = l & 31;
    const int kcBase = 2 * w + (l >> 5);

#pragma unroll
    for (int j = 0; j < KD / 32; ++j) {
        const int kc = kcBase + 8 * j;
        const int k0 = kc * 4;
        int row = row0 + r;
        if (row >= nRows) row = nRows - 1;
        const float4 v = *(const float4*)(in + (size_t)row * KD + k0);
        inT[k0 + 0][r] = v.x; inT[k0 + 1][r] = v.y; inT[k0 + 2][r] = v.z; inT[k0 + 3][r] = v.w;
    }
    __syncthreads();

    const int rg = w * 2 + (l >> 5);
    const int r0 = rg * 4;
    const int cc0 = (l & 31) * 4;

    float acc[4][4];
    if constexpr (MODE == 0) {
        const float4 bb = *(const float4*)(aux + cc0);
#pragma unroll
        for (int rr = 0; rr < 4; ++rr) {
            acc[rr][0] = bb.x; acc[rr][1] = bb.y; acc[rr][2] = bb.z; acc[rr][3] = bb.w;
        }
    } else {
#pragma unroll
        for (int rr = 0; rr < 4; ++rr) acc[rr][0] = acc[rr][1] = acc[rr][2] = acc[rr][3] = 0.f;
    }

#pragma unroll 4
    for (int k = 0; k < KD; ++k) {
        const float4 wv = *(const float4*)(W + (size_t)k * 128 + cc0);
        const float4 ea = *(const float4*)&inT[k][r0];
        const float ev[4] = {ea.x, ea.y, ea.z, ea.w};
#pragma unroll
        for (int rr = 0; rr < 4; ++rr) {
            acc[rr][0] += ev[rr] * wv.x; acc[rr][1] += ev[rr] * wv.y;
            acc[rr][2] += ev[rr] * wv.z; acc[rr][3] += ev[rr] * wv.w;
        }
    }

    float c0 = 0.f, c1 = 0.f, c2 = 0.f;
    if constexpr (MODE == 1) {
        const float a1 = *a1p, a2 = *a2p, b2 = *b2p;
        c0 = 1.f - a2 - b2;
        c1 = a2 + b2 * (1.f - a1);
        c2 = b2 * a1;
    }

#pragma unroll
    for (int rr = 0; rr < 4; ++rr) {
        const int row = row0 + r0 + rr;
        if (row < nRows) {
            float4 o = make_float4(acc[rr][0], acc[rr][1], acc[rr][2], acc[rr][3]);
            if constexpr (MODE == 1) {
                const size_t idx = (size_t)row * 128 + cc0;
                const float4 b1v = *(const float4*)(aux + idx);
                const float4 b2v = *(const float4*)(aux2 + idx);
                o.x = c0 * b1v.x + c1 * b2v.x + c2 * o.x;
                o.y = c0 * b1v.y + c1 * b2v.y + c2 * o.y;
                o.z = c0 * b1v.z + c1 * b2v.z + c2 * o.z;
                o.w = c0 * b1v.w + c1 * b2v.w + c2 * o.w;
            }
            *(float4*)(outp + (size_t)row * 128 + cc0) = o;
        }
    }
}

// ---------------- co-attention aggregation (FROZEN from round 8)
template <int K>
__global__ __launch_bounds__(256, 2) void coagg_kernel(
    const float* __restrict__ fa, const int* __restrict__ iDa, const int* __restrict__ iQa,
    float* __restrict__ oa,
    const float* __restrict__ fb, const int* __restrict__ iDb, const int* __restrict__ iQb,
    float* __restrict__ ob,
    const int nPer, const int relu)
{
    __shared__ float sL[4][K][K];
    __shared__ float sLT[4][K][K];
    __shared__ float sAC[4][K][K];
    __shared__ float sAS[4][K][K];
    __shared__ float sw_[4][K], su_[4][K];
    __shared__ __align__(16) float sHsum[4][768];

    const int t = threadIdx.x;
    const int wv = t >> 6, lane = t & 63;
    int n = blockIdx.x * 4 + wv;

    const float* feat; const int* idxD; const int* idxQ; float* outp;
    if (n < nPer) { feat = fa; idxD = iDa; idxQ = iQa; outp = oa; }
    else { n -= nPer; feat = fb; idxD = iDb; idxQ = iQb; outp = ob; }

    const float4* fp = (const float4*)feat;

    float4 d[K], q[K];
#pragma unroll
    for (int k = 0; k < K; ++k) {
        const int rD = idxD[n * K + k];
        const int rQ = idxQ[n * K + k];
        d[k] = fp[(size_t)rD * 64 + lane];
        q[k] = fp[(size_t)rQ * 64 + lane];
    }
    const float4 resid = fp[(size_t)n * 64 + lane];
#pragma unroll
    for (int k = 0; k < K; ++k) { OPAQUE4(d[k]); OPAQUE4(q[k]); }

#pragma unroll
    for (int k = 0; k < K; ++k) {
        const float4 dd = d[k];
#pragma unroll
        for (int m0 = 0; m0 < K; m0 += 2) {
            const float4 q0 = q[m0];
            float s0 = dd.x * q0.x + dd.y * q0.y + dd.z * q0.z + dd.w * q0.w;
            float s1 = 0.f;
            if (m0 + 1 < K) {
                const float4 q1 = q[m0 + 1];
                s1 = dd.x * q1.x + dd.y * q1.y + dd.z * q1.z + dd.w * q1.w;
            }
            asm volatile("v_permlane32_swap_b32 %0, %1" : "+v"(s0), "+v"(s1));
            float r = s0 + s1;
            r = dppAdd<0x111>(r);
            r = dppAdd<0x112>(r);
            r = dppAdd<0x114>(r);
            r = dppAdd<0x118>(r);
            r = dppAdd<0x142>(r);
            if (lane == 31) { sL[wv][k][m0] = r; sLT[wv][m0][k] = r; }
            if (lane == 63 && m0 + 1 < K) { sL[wv][k][m0 + 1] = r; sLT[wv][m0 + 1][k] = r; }
        }
    }

    {
        const int g = lane >> 4;
        const int r2 = lane & 15;
        if (g < 2 && r2 < K) {
            const float* Lrow = (g == 0) ? &sL[wv][r2][0] : &sLT[wv][r2][0];
            float* Arow       = (g == 0) ? &sAC[wv][r2][0] : &sAS[wv][r2][0];
            float e_[K], mx = -1e30f;
#pragma unroll
            for (int m = 0; m < K; ++m) mx = fmaxf(mx, Lrow[m]);
            float ssum = 0.f;
#pragma unroll
            for (int m = 0; m < K; ++m) { e_[m] = __expf(Lrow[m] - mx); ssum += e_[m]; }
            const float inv = 1.f / ssum;
#pragma unroll
            for (int m = 0; m < K; ++m) Arow[m] = e_[m] * inv;
        }
    }
    {
        const int m2 = lane - 32;
        if (m2 >= 0 && m2 < K) {
            float s = 0.f;
#pragma unroll
            for (int k2 = 0; k2 < K; ++k2) s += sAS[wv][k2][m2];
            sw_[wv][m2] = s;
        }
    }
    {
        const int j2 = lane - 48;
        if (j2 >= 0 && j2 < K) {
            float s = 0.f;
#pragma unroll
            for (int m = 0; m < K; ++m) s += sw_[wv][m] * sAC[wv][m][j2];
            su_[wv][j2] = s;
        }
    }

    float4 h0v = make_float4(0.f, 0.f, 0.f, 0.f);
    float4 h1v = make_float4(0.f, 0.f, 0.f, 0.f);
    float4 h2v = make_float4(0.f, 0.f, 0.f, 0.f);
#pragma unroll
    for (int kx = 0; kx < K; ++kx) {
        const float wk = sw_[wv][kx];
        const float uk = su_[wv][kx];
        const float4 qq = q[kx];
        const float4 dd = d[kx];
        h0v.x += qq.x;      h0v.y += qq.y;      h0v.z += qq.z;      h0v.w += qq.w;
        h1v.x += wk * dd.x; h1v.y += wk * dd.y; h1v.z += wk * dd.z; h1v.w += wk * dd.w;
        h2v.x += uk * qq.x; h2v.y += uk * qq.y; h2v.z += uk * qq.z; h2v.w += uk * qq.w;
    }
    ((float4*)&sHsum[wv][0])[lane]       = h0v;
    ((float4*)&sHsum[wv][0])[64 + lane]  = h1v;
    ((float4*)&sHsum[wv][0])[128 + lane] = h2v;

    float ov[4];
#pragma unroll
    for (int i = 0; i < 4; ++i) {
        const int f = lane * 4 + i;
        ov[i] = (sHsum[wv][3 * f] + sHsum[wv][3 * f + 1] + sHsum[wv][3 * f + 2])
                * (1.0f / (3.0f * K));
    }
    float4 o = make_float4(resid.x + ov[0], resid.y + ov[1],
                           resid.z + ov[2], resid.w + ov[3]);
    if (relu) {
        o.x = fmaxf(o.x, 0.f); o.y = fmaxf(o.y, 0.f);
        o.z = fmaxf(o.z, 0.f); o.w = fmaxf(o.w, 0.f);
    }
    ((float4*)outp)[(size_t)n * 64 + lane] = o;
}

extern "C" void kernel_launch(void* const* d_in, const int* in_sizes, int n_in,
                              void* d_out, int out_size, void* d_ws, size_t ws_size,
                              hipStream_t stream)
{
    const int* x        = (const int*)d_in[0];
    const int* idx_sim0 = (const int*)d_in[1];
    const int* idx_cor0 = (const int*)d_in[2];
    const int* idx_sim1 = (const int*)d_in[3];
    const int* idx_cor1 = (const int*)d_in[4];
    const float* e0s  = (const float*)d_in[5];
    const float* e1s  = (const float*)d_in[6];
    const float* e2s  = (const float*)d_in[7];
    const float* Wins = (const float*)d_in[8];
    const float* bins = (const float*)d_in[9];
    const float* Wouts= (const float*)d_in[10];
    const float* bouts= (const float*)d_in[11];
    const float* e0c  = (const float*)d_in[12];
    const float* e1c  = (const float*)d_in[13];
    const float* e2c  = (const float*)d_in[14];
    const float* Winc = (const float*)d_in[15];
    const float* binc = (const float*)d_in[16];
    const float* Woutc= (const float*)d_in[17];
    const float* boutc= (const float*)d_in[18];
    const float* Ws2c = (const float*)d_in[19];
    const float* Wc2s = (const float*)d_in[20];
    const float* a1 = (const float*)d_in[21];
    const float* a2 = (const float*)d_in[22];
    const float* b2 = (const float*)d_in[23];

    float* outSim = (float*)d_out;
    float* outCor = outSim + 6000 * 128;

    float* ws = (float*)d_ws;
    const size_t needMerged = (size_t)(2 * 16000 * 256 + 2 * 12000 * 256 + 2 * 6000 * 256 + 4 * 6000 * 128) * 4;
    const bool merged = ws_size >= needMerged;

    const int fcBlocks = (6000 + 31) / 32;   // 188 (fallback path)

    if (merged) {
        float* A0 = ws;
        float* A1 = A0 + 16000 * 256;
        float* B0 = A1 + 16000 * 256;
        float* B1 = B0 + 12000 * 256;
        float* C0 = B1 + 12000 * 256;
        float* C1 = C0 + 6000 * 256;

        embed_fc2_kernel<<<1000, 256, 0, stream>>>(x,
            e0s, e1s, e2s, Wins, bins, A0,
            e0c, e1c, e2c, Winc, binc, A1, 500);
        // sim: D=feat[idx_cor], Q=feat[idx_sim]; cor: swapped
        coagg_kernel<10><<<6000, 256, 0, stream>>>(
            A0, idx_cor0, idx_sim0, B0,
            A1, idx_sim0, idx_cor0, B1, 12000, 1);
        coagg_kernel<5><<<3000, 256, 0, stream>>>(
            B0, idx_cor1, idx_sim1, C0,
            B1, idx_sim1, idx_cor1, C1, 6000, 0);
        // fused: fc_out(both) + P/S + T1/T2 + combine -> d_out
        tail_fused_kernel<<<375, 256, 0, stream>>>(
            C0, C1, Wouts, bouts, Woutc, boutc, Ws2c, Wc2s,
            a1, a2, b2, outSim, outCor);
    } else {
        float* A = ws;
        float* B = A + 16000 * 256;
        float* C = B + 12000 * 256;
        float* simO = C + 6000 * 256;
        float* corO = simO + 6000 * 128;
        float* P    = corO + 6000 * 128;
        float* S    = P + 6000 * 128;

        for (int b = 0; b < 2; ++b) {
            const float* e0   = (b == 0) ? e0s : e0c;
            const float* e1   = (b == 0) ? e1s : e1c;
            const float* e2   = (b == 0) ? e2s : e2c;
            const float* Win  = (b == 0) ? Wins : Winc;
            const float* bin  = (b == 0) ? bins : binc;
            const float* Wout = (b == 0) ? Wouts : Woutc;
            const float* bout = (b == 0) ? bouts : boutc;
            const int* iD0 = (b == 0) ? idx_cor0 : idx_sim0;
            const int* iQ0 = (b == 0) ? idx_sim0 : idx_cor0;
            const int* iD1 = (b == 0) ? idx_cor1 : idx_sim1;
            const int* iQ1 = (b == 0) ? idx_sim1 : idx_cor1;
            float* branchOut = (b == 0) ? simO : corO;

            embed_fc2_kernel<<<500, 256, 0, stream>>>(x,
                e0, e1, e2, Win, bin, A,
                e0, e1, e2, Win, bin, A, 500);
            coagg_kernel<10><<<3000, 256, 0, stream>>>(
                A, iD0, iQ0, B, A, iD0, iQ0, B, 12000, 1);
            coagg_kernel<5><<<1500, 256, 0, stream>>>(
                B, iD1, iQ1, C, B, iD1, iQ1, C, 6000, 0);
            gemm32_kernel<256, 0><<<fcBlocks, 256, 0, stream>>>(
                C, Wout, bout, nullptr, branchOut,
                C, Wout, bout, nullptr, branchOut, fcBlocks, 6000, a1, a2, b2);
        }
        gemm32_kernel<128, 2><<<2 * fcBlocks, 256, 0, stream>>>(
            corO, Wc2s, nullptr, nullptr, P,
            simO, Ws2c, nullptr, nullptr, S, fcBlocks, 6000, a1, a2, b2);
        gemm32_kernel<128, 1><<<2 * fcBlocks, 256, 0, stream>>>(
            S, Wc2s, simO, P, outSim,
            P, Ws2c, corO, S, outCor, fcBlocks, 6000, a1, a2, b2);
    }
}

// Round 11
// 181.960 us; speedup vs baseline: 1.0591x; 1.0591x over previous
//
#include <hip/hip_runtime.h>

#define CH 256

// DPP helper: v += dpp_move(v); bound_ctrl=true => out-of-range lanes read 0.
template <int CTRL>
__device__ __forceinline__ float dppAdd(float v) {
    const int m = __builtin_amdgcn_update_dpp(0, __builtin_bit_cast(int, v), CTRL, 0xf, 0xf, true);
    return v + __builtin_bit_cast(float, m);
}

#define OPAQUE4(v) asm volatile("" : "+v"((v).x), "+v"((v).y), "+v"((v).z), "+v"((v).w))

// ---------------- embed + fc_input v2 (FROZEN from round 9)
__global__ __launch_bounds__(256) void embed_fc2_kernel(
    const int* __restrict__ x,
    const float* __restrict__ e0a, const float* __restrict__ e1a, const float* __restrict__ e2a,
    const float* __restrict__ Wina, const float* __restrict__ bina, float* __restrict__ h0a,
    const float* __restrict__ e0b, const float* __restrict__ e1b, const float* __restrict__ e2b,
    const float* __restrict__ Winb, const float* __restrict__ binb, float* __restrict__ h0b,
    const int blocksPer)
{
    __shared__ __align__(16) float eT[128][32];
    int bid = blockIdx.x;
    const float *e0, *e1, *e2, *Win, *bin;
    float* h0;
    if (bid < blocksPer) { e0 = e0a; e1 = e1a; e2 = e2a; Win = Wina; bin = bina; h0 = h0a; }
    else { bid -= blocksPer; e0 = e0b; e1 = e1b; e2 = e2b; Win = Winb; bin = binb; h0 = h0b; }

    const int row0 = bid * 32;
    const int t = threadIdx.x;
    const int w = t >> 6, l = t & 63;
    const int r = l & 31;
    const int kcBase = 2 * w + (l >> 5);

#pragma unroll
    for (int j = 0; j < 4; ++j) {
        const int kc = kcBase + 8 * j;
        const int k0 = kc * 4;
        const int row = row0 + r;
        float4 v;
        if (kc < 16)      v = *(const float4*)(e0 + (size_t)x[row * 3 + 0] * 64 + k0);
        else if (kc < 24) v = *(const float4*)(e1 + (size_t)x[row * 3 + 1] * 32 + (k0 - 64));
        else              v = *(const float4*)(e2 + (size_t)x[row * 3 + 2] * 32 + (k0 - 96));
        eT[k0 + 0][r] = v.x; eT[k0 + 1][r] = v.y; eT[k0 + 2][r] = v.z; eT[k0 + 3][r] = v.w;
    }
    __syncthreads();

    const float4 bb = *(const float4*)(bin + l * 4);
    float acc[8][4];
#pragma unroll
    for (int rr = 0; rr < 8; ++rr) {
        acc[rr][0] = bb.x; acc[rr][1] = bb.y; acc[rr][2] = bb.z; acc[rr][3] = bb.w;
    }
#pragma unroll 4
    for (int k = 0; k < 128; ++k) {
        const float4 wv = *(const float4*)(Win + (size_t)k * 256 + l * 4);
        const float4 ea = *(const float4*)&eT[k][w * 8];
        const float4 eb = *(const float4*)&eT[k][w * 8 + 4];
        const float ev[8] = {ea.x, ea.y, ea.z, ea.w, eb.x, eb.y, eb.z, eb.w};
#pragma unroll
        for (int rr = 0; rr < 8; ++rr) {
            acc[rr][0] += ev[rr] * wv.x; acc[rr][1] += ev[rr] * wv.y;
            acc[rr][2] += ev[rr] * wv.z; acc[rr][3] += ev[rr] * wv.w;
        }
    }
#pragma unroll
    for (int rr = 0; rr < 8; ++rr) {
        float4 o = make_float4(acc[rr][0], acc[rr][1], acc[rr][2], acc[rr][3]);
        *(float4*)(h0 + (size_t)(row0 + w * 8 + rr) * 256 + l * 4) = o;
    }
}

// ---------------- generic 32-row register-tiled GEMM, Cout=128 (round-9 proven)
// MODE 0: out = in@W + bias(aux)
// MODE 1: out = c0*aux + c1*aux2 + c2*(in@W)
// MODE 2: out = in@W
template <int KD, int MODE>
__global__ __launch_bounds__(256) void gemm32_kernel(
    const float* __restrict__ ina, const float* __restrict__ Wa,
    const float* __restrict__ auxa, const float* __restrict__ aux2a, float* __restrict__ oa,
    const float* __restrict__ inb, const float* __restrict__ Wb,
    const float* __restrict__ auxb, const float* __restrict__ aux2b, float* __restrict__ ob,
    const int blocksPer, const int nRows,
    const float* __restrict__ a1p, const float* __restrict__ a2p, const float* __restrict__ b2p)
{
    __shared__ __align__(16) float inT[KD][32];
    int bid = blockIdx.x;
    const float *in, *W, *aux, *aux2; float* outp;
    if (bid < blocksPer) { in = ina; W = Wa; aux = auxa; aux2 = aux2a; outp = oa; }
    else { bid -= blocksPer; in = inb; W = Wb; aux = auxb; aux2 = aux2b; outp = ob; }

    const int row0 = bid * 32;
    const int t = threadIdx.x;
    const int w = t >> 6, l = t & 63;
    const int r = l & 31;
    const int kcBase = 2 * w + (l >> 5);

#pragma unroll
    for (int j = 0; j < KD / 32; ++j) {
        const int kc = kcBase + 8 * j;
        const int k0 = kc * 4;
        int row = row0 + r;
        if (row >= nRows) row = nRows - 1;
        const float4 v = *(const float4*)(in + (size_t)row * KD + k0);
        inT[k0 + 0][r] = v.x; inT[k0 + 1][r] = v.y; inT[k0 + 2][r] = v.z; inT[k0 + 3][r] = v.w;
    }
    __syncthreads();

    const int rg = w * 2 + (l >> 5);
    const int r0 = rg * 4;
    const int cc0 = (l & 31) * 4;

    float acc[4][4];
    if constexpr (MODE == 0) {
        const float4 bb = *(const float4*)(aux + cc0);
#pragma unroll
        for (int rr = 0; rr < 4; ++rr) {
            acc[rr][0] = bb.x; acc[rr][1] = bb.y; acc[rr][2] = bb.z; acc[rr][3] = bb.w;
        }
    } else {
#pragma unroll
        for (int rr = 0; rr < 4; ++rr) acc[rr][0] = acc[rr][1] = acc[rr][2] = acc[rr][3] = 0.f;
    }

#pragma unroll 4
    for (int k = 0; k < KD; ++k) {
        const float4 wv = *(const float4*)(W + (size_t)k * 128 + cc0);
        const float4 ea = *(const float4*)&inT[k][r0];
        const float ev[4] = {ea.x, ea.y, ea.z, ea.w};
#pragma unroll
        for (int rr = 0; rr < 4; ++rr) {
            acc[rr][0] += ev[rr] * wv.x; acc[rr][1] += ev[rr] * wv.y;
            acc[rr][2] += ev[rr] * wv.z; acc[rr][3] += ev[rr] * wv.w;
        }
    }

    float c0 = 0.f, c1 = 0.f, c2 = 0.f;
    if constexpr (MODE == 1) {
        const float a1 = *a1p, a2 = *a2p, b2 = *b2p;
        c0 = 1.f - a2 - b2;
        c1 = a2 + b2 * (1.f - a1);
        c2 = b2 * a1;
    }

#pragma unroll
    for (int rr = 0; rr < 4; ++rr) {
        const int row = row0 + r0 + rr;
        if (row < nRows) {
            float4 o = make_float4(acc[rr][0], acc[rr][1], acc[rr][2], acc[rr][3]);
            if constexpr (MODE == 1) {
                const size_t idx = (size_t)row * 128 + cc0;
                const float4 b1v = *(const float4*)(aux + idx);
                const float4 b2v = *(const float4*)(aux2 + idx);
                o.x = c0 * b1v.x + c1 * b2v.x + c2 * o.x;
                o.y = c0 * b1v.y + c1 * b2v.y + c2 * o.y;
                o.z = c0 * b1v.z + c1 * b2v.z + c2 * o.z;
                o.w = c0 * b1v.w + c1 * b2v.w + c2 * o.w;
            }
            *(float4*)(outp + (size_t)row * 128 + cc0) = o;
        }
    }
}

// ---------------- co-attention aggregation: round-8 structure, split softmax
// (sLT dual-store + merged softmax reverted: it measured +3 µs in round 7)
template <int K>
__global__ __launch_bounds__(256, 2) void coagg_kernel(
    const float* __restrict__ fa, const int* __restrict__ iDa, const int* __restrict__ iQa,
    float* __restrict__ oa,
    const float* __restrict__ fb, const int* __restrict__ iDb, const int* __restrict__ iQb,
    float* __restrict__ ob,
    const int nPer, const int relu)
{
    __shared__ float sL[4][K][K];
    __shared__ float sAC[4][K][K];
    __shared__ float sAS[4][K][K];
    __shared__ float sw_[4][K], su_[4][K];
    __shared__ __align__(16) float sHsum[4][768];

    const int t = threadIdx.x;
    const int wv = t >> 6, lane = t & 63;
    int n = blockIdx.x * 4 + wv;

    const float* feat; const int* idxD; const int* idxQ; float* outp;
    if (n < nPer) { feat = fa; idxD = iDa; idxQ = iQa; outp = oa; }
    else { n -= nPer; feat = fb; idxD = iDb; idxQ = iQb; outp = ob; }

    const float4* fp = (const float4*)feat;

    float4 d[K], q[K];
#pragma unroll
    for (int k = 0; k < K; ++k) {
        const int rD = idxD[n * K + k];
        const int rQ = idxQ[n * K + k];
        d[k] = fp[(size_t)rD * 64 + lane];
        q[k] = fp[(size_t)rQ * 64 + lane];
    }
    const float4 resid = fp[(size_t)n * 64 + lane];
#pragma unroll
    for (int k = 0; k < K; ++k) { OPAQUE4(d[k]); OPAQUE4(q[k]); }

    // L-phase: verified 2-pair permlane32_swap + DPP ladder
#pragma unroll
    for (int k = 0; k < K; ++k) {
        const float4 dd = d[k];
#pragma unroll
        for (int m0 = 0; m0 < K; m0 += 2) {
            const float4 q0 = q[m0];
            float s0 = dd.x * q0.x + dd.y * q0.y + dd.z * q0.z + dd.w * q0.w;
            float s1 = 0.f;
            if (m0 + 1 < K) {
                const float4 q1 = q[m0 + 1];
                s1 = dd.x * q1.x + dd.y * q1.y + dd.z * q1.z + dd.w * q1.w;
            }
            asm volatile("v_permlane32_swap_b32 %0, %1" : "+v"(s0), "+v"(s1));
            float r = s0 + s1;
            r = dppAdd<0x111>(r);
            r = dppAdd<0x112>(r);
            r = dppAdd<0x114>(r);
            r = dppAdd<0x118>(r);
            r = dppAdd<0x142>(r);
            if (lane == 31) sL[wv][k][m0] = r;
            if (lane == 63 && m0 + 1 < K) sL[wv][k][m0 + 1] = r;
        }
    }

    // stage A: split softmaxes (lanes 0..K-1: AC rows; lanes 16..16+K-1: AS cols)
    if (lane < K) {
        float e_[K], mx = -1e30f;
#pragma unroll
        for (int m = 0; m < K; ++m) mx = fmaxf(mx, sL[wv][lane][m]);
        float ssum = 0.f;
#pragma unroll
        for (int m = 0; m < K; ++m) { e_[m] = __expf(sL[wv][lane][m] - mx); ssum += e_[m]; }
        const float inv = 1.f / ssum;
#pragma unroll
        for (int m = 0; m < K; ++m) sAC[wv][lane][m] = e_[m] * inv;
    }
    {
        const int c = lane - 16;
        if (c >= 0 && c < K) {
            float e_[K], mx = -1e30f;
#pragma unroll
            for (int m = 0; m < K; ++m) mx = fmaxf(mx, sL[wv][m][c]);
            float ssum = 0.f;
#pragma unroll
            for (int m = 0; m < K; ++m) { e_[m] = __expf(sL[wv][m][c] - mx); ssum += e_[m]; }
            const float inv = 1.f / ssum;
#pragma unroll
            for (int m = 0; m < K; ++m) sAS[wv][c][m] = e_[m] * inv;
        }
    }
    // stage B: w[m] = colsum(AS)   (lanes 32..32+K-1)
    {
        const int m2 = lane - 32;
        if (m2 >= 0 && m2 < K) {
            float s = 0.f;
#pragma unroll
            for (int k2 = 0; k2 < K; ++k2) s += sAS[wv][k2][m2];
            sw_[wv][m2] = s;
        }
    }
    // stage C: u[j] = sum_m w[m]*AC[m][j]   (lanes 48..48+K-1)
    {
        const int j2 = lane - 48;
        if (j2 >= 0 && j2 < K) {
            float s = 0.f;
#pragma unroll
            for (int m = 0; m < K; ++m) s += sw_[wv][m] * sAC[wv][m][j2];
            su_[wv][j2] = s;
        }
    }

    // stage D: weighted row sums
    float4 h0v = make_float4(0.f, 0.f, 0.f, 0.f);
    float4 h1v = make_float4(0.f, 0.f, 0.f, 0.f);
    float4 h2v = make_float4(0.f, 0.f, 0.f, 0.f);
#pragma unroll
    for (int kx = 0; kx < K; ++kx) {
        const float wk = sw_[wv][kx];
        const float uk = su_[wv][kx];
        const float4 qq = q[kx];
        const float4 dd = d[kx];
        h0v.x += qq.x;      h0v.y += qq.y;      h0v.z += qq.z;      h0v.w += qq.w;
        h1v.x += wk * dd.x; h1v.y += wk * dd.y; h1v.z += wk * dd.z; h1v.w += wk * dd.w;
        h2v.x += uk * qq.x; h2v.y += uk * qq.y; h2v.z += uk * qq.z; h2v.w += uk * qq.w;
    }
    ((float4*)&sHsum[wv][0])[lane]       = h0v;
    ((float4*)&sHsum[wv][0])[64 + lane]  = h1v;
    ((float4*)&sHsum[wv][0])[128 + lane] = h2v;

    // stage E: pool3 + mean_k + residual
    float ov[4];
#pragma unroll
    for (int i = 0; i < 4; ++i) {
        const int f = lane * 4 + i;
        ov[i] = (sHsum[wv][3 * f] + sHsum[wv][3 * f + 1] + sHsum[wv][3 * f + 2])
                * (1.0f / (3.0f * K));
    }
    float4 o = make_float4(resid.x + ov[0], resid.y + ov[1],
                           resid.z + ov[2], resid.w + ov[3]);
    if (relu) {
        o.x = fmaxf(o.x, 0.f); o.y = fmaxf(o.y, 0.f);
        o.z = fmaxf(o.z, 0.f); o.w = fmaxf(o.w, 0.f);
    }
    ((float4*)outp)[(size_t)n * 64 + lane] = o;
}

extern "C" void kernel_launch(void* const* d_in, const int* in_sizes, int n_in,
                              void* d_out, int out_size, void* d_ws, size_t ws_size,
                              hipStream_t stream)
{
    const int* x        = (const int*)d_in[0];
    const int* idx_sim0 = (const int*)d_in[1];
    const int* idx_cor0 = (const int*)d_in[2];
    const int* idx_sim1 = (const int*)d_in[3];
    const int* idx_cor1 = (const int*)d_in[4];
    const float* e0s  = (const float*)d_in[5];
    const float* e1s  = (const float*)d_in[6];
    const float* e2s  = (const float*)d_in[7];
    const float* Wins = (const float*)d_in[8];
    const float* bins = (const float*)d_in[9];
    const float* Wouts= (const float*)d_in[10];
    const float* bouts= (const float*)d_in[11];
    const float* e0c  = (const float*)d_in[12];
    const float* e1c  = (const float*)d_in[13];
    const float* e2c  = (const float*)d_in[14];
    const float* Winc = (const float*)d_in[15];
    const float* binc = (const float*)d_in[16];
    const float* Woutc= (const float*)d_in[17];
    const float* boutc= (const float*)d_in[18];
    const float* Ws2c = (const float*)d_in[19];
    const float* Wc2s = (const float*)d_in[20];
    const float* a1 = (const float*)d_in[21];
    const float* a2 = (const float*)d_in[22];
    const float* b2 = (const float*)d_in[23];

    float* outSim = (float*)d_out;
    float* outCor = outSim + 6000 * 128;

    float* ws = (float*)d_ws;
    const size_t needMerged = (size_t)(2 * 16000 * 256 + 2 * 12000 * 256 + 2 * 6000 * 256 + 4 * 6000 * 128) * 4;
    const bool merged = ws_size >= needMerged;

    const int fcBlocks = (6000 + 31) / 32;   // 188

    if (merged) {
        float* A0 = ws;
        float* A1 = A0 + 16000 * 256;
        float* B0 = A1 + 16000 * 256;
        float* B1 = B0 + 12000 * 256;
        float* C0 = B1 + 12000 * 256;
        float* C1 = C0 + 6000 * 256;
        float* simO = C1 + 6000 * 256;
        float* corO = simO + 6000 * 128;
        float* P    = corO + 6000 * 128;
        float* S    = P + 6000 * 128;

        embed_fc2_kernel<<<1000, 256, 0, stream>>>(x,
            e0s, e1s, e2s, Wins, bins, A0,
            e0c, e1c, e2c, Winc, binc, A1, 500);
        // sim: D=feat[idx_cor], Q=feat[idx_sim]; cor: swapped
        coagg_kernel<10><<<6000, 256, 0, stream>>>(
            A0, idx_cor0, idx_sim0, B0,
            A1, idx_sim0, idx_cor0, B1, 12000, 1);
        coagg_kernel<5><<<3000, 256, 0, stream>>>(
            B0, idx_cor1, idx_sim1, C0,
            B1, idx_sim1, idx_cor1, C1, 6000, 0);
        gemm32_kernel<256, 0><<<2 * fcBlocks, 256, 0, stream>>>(
            C0, Wouts, bouts, nullptr, simO,
            C1, Woutc, boutc, nullptr, corO, fcBlocks, 6000, a1, a2, b2);
        // P = cor@Wc2s ; S = sim@Ws2c
        gemm32_kernel<128, 2><<<2 * fcBlocks, 256, 0, stream>>>(
            corO, Wc2s, nullptr, nullptr, P,
            simO, Ws2c, nullptr, nullptr, S, fcBlocks, 6000, a1, a2, b2);
        // z2sim = c0*sim + c1*P + c2*(S@Wc2s) ; z2cor = c0*cor + c1*S + c2*(P@Ws2c)
        gemm32_kernel<128, 1><<<2 * fcBlocks, 256, 0, stream>>>(
            S, Wc2s, simO, P, outSim,
            P, Ws2c, corO, S, outCor, fcBlocks, 6000, a1, a2, b2);
    } else {
        float* A = ws;
        float* B = A + 16000 * 256;
        float* C = B + 12000 * 256;
        float* simO = C + 6000 * 256;
        float* corO = simO + 6000 * 128;
        float* P    = corO + 6000 * 128;
        float* S    = P + 6000 * 128;

        for (int b = 0; b < 2; ++b) {
            const float* e0   = (b == 0) ? e0s : e0c;
            const float* e1   = (b == 0) ? e1s : e1c;
            const float* e2   = (b == 0) ? e2s : e2c;
            const float* Win  = (b == 0) ? Wins : Winc;
            const float* bin  = (b == 0) ? bins : binc;
            const float* Wout = (b == 0) ? Wouts : Woutc;
            const float* bout = (b == 0) ? bouts : boutc;
            const int* iD0 = (b == 0) ? idx_cor0 : idx_sim0;
            const int* iQ0 = (b == 0) ? idx_sim0 : idx_cor0;
            const int* iD1 = (b == 0) ? idx_cor1 : idx_sim1;
            const int* iQ1 = (b == 0) ? idx_sim1 : idx_cor1;
            float* branchOut = (b == 0) ? simO : corO;

            embed_fc2_kernel<<<500, 256, 0, stream>>>(x,
                e0, e1, e2, Win, bin, A,
                e0, e1, e2, Win, bin, A, 500);
            coagg_kernel<10><<<3000, 256, 0, stream>>>(
                A, iD0, iQ0, B, A, iD0, iQ0, B, 12000, 1);
            coagg_kernel<5><<<1500, 256, 0, stream>>>(
                B, iD1, iQ1, C, B, iD1, iQ1, C, 6000, 0);
            gemm32_kernel<256, 0><<<fcBlocks, 256, 0, stream>>>(
                C, Wout, bout, nullptr, branchOut,
                C, Wout, bout, nullptr, branchOut, fcBlocks, 6000, a1, a2, b2);
        }
        gemm32_kernel<128, 2><<<2 * fcBlocks, 256, 0, stream>>>(
            corO, Wc2s, nullptr, nullptr, P,
            simO, Ws2c, nullptr, nullptr, S, fcBlocks, 6000, a1, a2, b2);
        gemm32_kernel<128, 1><<<2 * fcBlocks, 256, 0, stream>>>(
            S, Wc2s, simO, P, outSim,
            P, Ws2c, corO, S, outCor, fcBlocks, 6000, a1, a2, b2);
    }
}